// Round 6
// baseline (1063.653 us; speedup 1.0000x reference)
//
#include <hip/hip_runtime.h>
#include <cstdint>

#define TOK   8192
#define DIM   1024
#define NE    8
#define HID   4096
#define CAP   8320
#define MAXRB 136   // max total 128-row blocks across experts

typedef __attribute__((ext_vector_type(4))) float f32x4;
typedef __attribute__((ext_vector_type(8))) short s16x8;

__device__ inline unsigned short f2bf(float f) {
  union { float f; unsigned u; } v; v.f = f;
  unsigned r = v.u + 0x7FFFu + ((v.u >> 16) & 1u);
  return (unsigned short)(r >> 16);
}
__device__ inline float bf2f(unsigned short u) {
  union { unsigned u; float f; } v; v.u = ((unsigned)u) << 16;
  return v.f;
}

// async global->LDS, 16B per lane. LDS dest is wave-uniform base + lane*16.
__device__ __forceinline__ void gload_lds16(const void* gptr, void* lptr) {
  __builtin_amdgcn_global_load_lds(
      (const __attribute__((address_space(1))) unsigned*)gptr,
      (__attribute__((address_space(3))) unsigned*)lptr, 16, 0, 0);
}

// Decode compacted work id -> (e, nb, rb). meta[0..8]=rboff (cumulative row-blocks,
// rboff[0]=0), meta[9]=nrb_tot. Order: nb outer, (e, rb) inner (rb innermost).
// XCD-chunked: b&7 selects the XCD-contiguous chunk (ntot % 8 == 0 always).
__device__ __forceinline__ bool decode_work(int b, const int* __restrict__ meta,
                                            int nb_total, int& e, int& nb, int& rb) {
  const int nrbtot = meta[9];
  const int ntot = nrbtot * nb_total;
  if (b >= ntot) return false;
  const int q = ntot >> 3;
  const int wid = (b & 7) * q + (b >> 3);   // bijective onto [0, ntot)
  nb = wid / nrbtot;
  const int rem = wid - nb * nrbtot;
  e = 0;
#pragma unroll
  for (int k = 1; k < 8; k++) e += (rem >= meta[k]);
  rb = rem - meta[e];
  return true;
}

// ---------------- router: one wave per token, fp32 exact; also casts x->bf16 ----------------
__global__ __launch_bounds__(256) void router_kernel(const float* __restrict__ x,
                                                     const float* __restrict__ noise,
                                                     const float* __restrict__ Wg,
                                                     const float* __restrict__ bg,
                                                     const float* __restrict__ Wn,
                                                     const float* __restrict__ bn,
                                                     int* __restrict__ cnt,
                                                     int* __restrict__ tokL,
                                                     float* __restrict__ gateL,
                                                     int* __restrict__ tokmap,
                                                     unsigned short* __restrict__ xb) {
  int t = blockIdx.x * 4 + (threadIdx.x >> 6);
  int lane = threadIdx.x & 63;
  float ag[8] = {0, 0, 0, 0, 0, 0, 0, 0};
  float an[8] = {0, 0, 0, 0, 0, 0, 0, 0};
  const float* xr = x + (size_t)t * DIM;
  unsigned short* xbr = xb + (size_t)t * DIM;
  for (int d0 = lane * 4; d0 < DIM; d0 += 256) {
    f32x4 xv = *(const f32x4*)(xr + d0);
    ushort4 o;
    o.x = f2bf(xv[0]); o.y = f2bf(xv[1]); o.z = f2bf(xv[2]); o.w = f2bf(xv[3]);
    *(ushort4*)(xbr + d0) = o;
#pragma unroll
    for (int q = 0; q < 4; q++) {
      float xq = xv[q];
      const float* wg = Wg + (size_t)(d0 + q) * 8;
      const float* wn = Wn + (size_t)(d0 + q) * 8;
      f32x4 g0 = *(const f32x4*)(wg);
      f32x4 g1 = *(const f32x4*)(wg + 4);
      f32x4 n0 = *(const f32x4*)(wn);
      f32x4 n1 = *(const f32x4*)(wn + 4);
      ag[0] += xq * g0[0]; ag[1] += xq * g0[1]; ag[2] += xq * g0[2]; ag[3] += xq * g0[3];
      ag[4] += xq * g1[0]; ag[5] += xq * g1[1]; ag[6] += xq * g1[2]; ag[7] += xq * g1[3];
      an[0] += xq * n0[0]; an[1] += xq * n0[1]; an[2] += xq * n0[2]; an[3] += xq * n0[3];
      an[4] += xq * n1[0]; an[5] += xq * n1[1]; an[6] += xq * n1[2]; an[7] += xq * n1[3];
    }
  }
#pragma unroll
  for (int off = 32; off >= 1; off >>= 1) {
#pragma unroll
    for (int e = 0; e < 8; e++) {
      ag[e] += __shfl_xor(ag[e], off);
      an[e] += __shfl_xor(an[e], off);
    }
  }
  if (lane == 0) {
    float v[8];
#pragma unroll
    for (int e = 0; e < 8; e++) {
      float lg = ag[e] + bg[e];
      float ln = an[e] + bn[e];
      float sp = (ln > 20.f) ? ln : log1pf(expf(ln));  // stable softplus
      v[e] = lg + noise[(size_t)t * 8 + e] * sp;
    }
    int i1 = 0; float m1 = v[0];
#pragma unroll
    for (int e = 1; e < 8; e++) { if (v[e] > m1) { m1 = v[e]; i1 = e; } }
    int i2 = -1; float m2 = -1e30f;
#pragma unroll
    for (int e = 0; e < 8; e++) { if (e != i1 && v[e] > m2) { m2 = v[e]; i2 = e; } }
    float e2 = expf(m2 - m1);
    float denom = 1.f + e2;
    float g1 = 1.f / denom;
    float g2 = e2 / denom;
    int p1 = atomicAdd(&cnt[i1], 1);
    tokL[i1 * CAP + p1] = t; gateL[i1 * CAP + p1] = g1;
    int p2 = atomicAdd(&cnt[i2], 1);
    tokL[i2 * CAP + p2] = t; gateL[i2 * CAP + p2] = g2;
    tokmap[t * 2 + 0] = (i1 << 20) | p1;
    tokmap[t * 2 + 1] = (i2 << 20) | p2;
  }
}

// ---------------- pad lists to 128-multiples; prefix sums; publish work-list meta ----------------
__global__ __launch_bounds__(256) void pad_kernel(const int* __restrict__ cnt,
                                                  int* __restrict__ hoff,
                                                  int* __restrict__ tokL,
                                                  float* __restrict__ gateL,
                                                  int* __restrict__ meta) {
  __shared__ int cp_s[8];
  if (threadIdx.x == 0) {
    int off = 0, rbsum = 0;
    for (int e = 0; e < 8; e++) {
      int c = cnt[e];
      int cp = (c + 127) & ~127;
      cp_s[e] = cp;
      hoff[e] = off;
      off += cp;
      meta[e] = rbsum;       // rboff[e]
      rbsum += cp >> 7;
    }
    meta[8] = rbsum;         // rboff[8]
    meta[9] = rbsum;         // nrb_tot
  }
  __syncthreads();
  for (int e = 0; e < 8; e++) {
    int c = cnt[e], cp = cp_s[e];
    for (int i = c + threadIdx.x; i < cp; i += 256) {
      tokL[e * CAP + i] = 0;
      gateL[e * CAP + i] = 0.f;
    }
  }
}

// ---------------- fused-transpose GEMM ----------------
// C[128 x 128] per block. A: bf16, gload_lds dbuf (round-3-verified path).
// B: read DIRECTLY from original fp32 W [E][KD][ND]; per K-tile each thread reads
// 4 coalesced f32x4 rows, packs k-pairs to bf16, ds_writes transposed into
// Bs[128][40] (80 B row stride -> b128-aligned; slot XOR (n>>2)&3 -> writes <=4-way,
// reads conflict-free). ONE __syncthreads per K-tile (its vmcnt(0) drains only the
// A-gloads issued a full body earlier; B-regs are compiler-tracked). T14 issue-early/
// write-late for B. 36.5 KB LDS -> 3-4 blocks/CU (restores round-3's TLP).
template <int KD, int ND, int NBT, bool GATHER, bool RELU>
__global__ __launch_bounds__(256, 3) void gemm_fused_kernel(
    const unsigned short* __restrict__ A,  // xb (gather) or hbuf (dense), bf16 [rows][KD]
    const float* __restrict__ W,           // ORIGINAL fp32 [E][KD][ND]
    const float* __restrict__ bias,        // fp32 [E][ND]
    const int* __restrict__ tokL,
    const int* __restrict__ meta,
    const int* __restrict__ hoff,
    unsigned short* __restrict__ outp) {   // [rows][ND] bf16
  int e, nb, rb;
  if (!decode_work(blockIdx.x, meta, NBT, e, nb, rb)) return;
  const int row0 = hoff[e] + rb * 128;
  const int n0 = nb * 128;

  __shared__ unsigned short As[2 * 128 * 32];  // 16 KB dbuf (linear: gload dest)
  __shared__ unsigned short Bs[2 * 128 * 40];  // 20 KB dbuf, transposed+padded
  __shared__ int toks[128];

  const int tid = threadIdx.x;
  if (GATHER) {
    if (tid < 128) toks[tid] = tokL[e * CAP + rb * 128 + tid];
    __syncthreads();
  }

  // ---- A staging (round-3 verbatim + dbuf) ----
  const int ar = tid >> 2;         // row 0..63 (and +64)
  const int ac = (tid & 3) << 3;   // bf16 col slot 0,8,16,24
  const unsigned short* gA0;
  const unsigned short* gA1;
  if (GATHER) {
    gA0 = A + (size_t)toks[ar] * KD + ac;
    gA1 = A + (size_t)toks[64 + ar] * KD + ac;
  } else {
    gA0 = A + (size_t)(row0 + ar) * KD + ac;
    gA1 = A + (size_t)(row0 + 64 + ar) * KD + ac;
  }

  // ---- B staging map: thread -> (n4 = (tid&31)*4, kp = tid>>5 and +8) ----
  const int bn4 = (tid & 31) * 4;
  const int bkp = tid >> 5;               // 0..7
  const int sx  = tid & 3;                // (bn4>>2)&3
  const int s0  = ((bkp >> 2) ^ sx) * 8 + (bkp & 3) * 2;        // short offset in row
  const int s1  = (((bkp >> 2) + 2) ^ sx) * 8 + (bkp & 3) * 2;  // pass 2 (k+16)
  const float* Wb = W + (size_t)e * KD * ND + n0 + bn4;

  const int lane = tid & 63;
  const int w = tid >> 6;
  const int wm = (w >> 1) * 64;
  const int wn = (w & 1) * 64;
  const int fr = lane & 15;
  const int fq = lane >> 4;

  f32x4 acc[4][4];
#pragma unroll
  for (int i = 0; i < 4; i++)
#pragma unroll
    for (int j = 0; j < 4; j++) acc[i][j] = (f32x4){0.f, 0.f, 0.f, 0.f};

  const int NT = KD / 32;

  // ---- prologue: stage tile 0 ----
  {
    gload_lds16(gA0, As + w * 512);
    gload_lds16(gA1, As + w * 512 + 2048);
    gA0 += 32; gA1 += 32;
    const float* wr = Wb + (size_t)(2 * bkp) * ND;
    f32x4 p0a = *(const f32x4*)(wr);
    f32x4 p0b = *(const f32x4*)(wr + ND);
    f32x4 p1a = *(const f32x4*)(wr + (size_t)16 * ND);
    f32x4 p1b = *(const f32x4*)(wr + (size_t)17 * ND);
    unsigned short* bs = Bs;
#pragma unroll
    for (int j = 0; j < 4; j++) {
      *(unsigned*)(bs + (bn4 + j) * 40 + s0) =
          (unsigned)f2bf(p0a[j]) | ((unsigned)f2bf(p0b[j]) << 16);
      *(unsigned*)(bs + (bn4 + j) * 40 + s1) =
          (unsigned)f2bf(p1a[j]) | ((unsigned)f2bf(p1b[j]) << 16);
    }
  }

  for (int t = 0; t < NT; ++t) {
    __syncthreads();  // vmcnt(0)+lgkm(0)+barrier: A(t) landed, Bs(t) visible
    const int cur = t & 1, nxt = cur ^ 1;
    const bool pf = (t + 1) < NT;
    f32x4 p0a, p0b, p1a, p1b;
    if (pf) {
      gload_lds16(gA0, As + nxt * 4096 + w * 512);
      gload_lds16(gA1, As + nxt * 4096 + w * 512 + 2048);
      gA0 += 32; gA1 += 32;
      const float* wr = Wb + (size_t)((t + 1) * 32 + 2 * bkp) * ND;
      p0a = *(const f32x4*)(wr);
      p0b = *(const f32x4*)(wr + ND);
      p1a = *(const f32x4*)(wr + (size_t)16 * ND);
      p1b = *(const f32x4*)(wr + (size_t)17 * ND);
    }
    const unsigned short* Asc = As + cur * 4096;
    const unsigned short* Bsc = Bs + cur * 5120;
    s16x8 af[4], bf[4];
#pragma unroll
    for (int i = 0; i < 4; i++)
      af[i] = *(const s16x8*)(Asc + (wm + i * 16 + fr) * 32 + fq * 8);
#pragma unroll
    for (int j = 0; j < 4; j++) {
      int col = wn + j * 16 + fr;
      bf[j] = *(const s16x8*)(Bsc + col * 40 + ((fq ^ ((col >> 2) & 3)) << 3));
    }
    __builtin_amdgcn_s_setprio(1);
#pragma unroll
    for (int i = 0; i < 4; i++)
#pragma unroll
      for (int j = 0; j < 4; j++)
        acc[i][j] = __builtin_amdgcn_mfma_f32_16x16x32_bf16(af[i], bf[j], acc[i][j], 0, 0, 0);
    __builtin_amdgcn_s_setprio(0);
    if (pf) {
      unsigned short* bs = Bs + nxt * 5120;
#pragma unroll
      for (int j = 0; j < 4; j++) {
        *(unsigned*)(bs + (bn4 + j) * 40 + s0) =
            (unsigned)f2bf(p0a[j]) | ((unsigned)f2bf(p0b[j]) << 16);
        *(unsigned*)(bs + (bn4 + j) * 40 + s1) =
            (unsigned)f2bf(p1a[j]) | ((unsigned)f2bf(p1b[j]) << 16);
      }
    }
  }

  // ---- epilogue (round-3 verbatim) ----
  const float* bp = bias + (size_t)e * ND + n0 + wn;
#pragma unroll
  for (int j = 0; j < 4; j++) {
    float bb = bp[j * 16 + fr];
#pragma unroll
    for (int i = 0; i < 4; i++)
#pragma unroll
      for (int v = 0; v < 4; v++) {
        float val = acc[i][j][v] + bb;
        if (RELU) val = fmaxf(val, 0.f);
        int m = wm + i * 16 + fq * 4 + v;
        outp[(size_t)(row0 + m) * ND + n0 + wn + j * 16 + fr] = f2bf(val);
      }
  }
}

// ---------------- combine: out[t] = g1*ybuf[row1] + g2*ybuf[row2] (dense, coalesced)
__global__ __launch_bounds__(256) void combine_kernel(const unsigned short* __restrict__ ybuf,
                                                      const int* __restrict__ tokmap,
                                                      const float* __restrict__ gateL,
                                                      const int* __restrict__ hoff,
                                                      float* __restrict__ out) {
  const int t = blockIdx.x;
  const int m1 = tokmap[t * 2 + 0];
  const int m2 = tokmap[t * 2 + 1];
  const int e1 = m1 >> 20, p1 = m1 & 0xFFFFF;
  const int e2 = m2 >> 20, p2 = m2 & 0xFFFFF;
  const float g1 = gateL[e1 * CAP + p1];
  const float g2 = gateL[e2 * CAP + p2];
  const size_t r1 = (size_t)(hoff[e1] + p1) * DIM;
  const size_t r2 = (size_t)(hoff[e2] + p2) * DIM;
  const int d = threadIdx.x * 4;
  ushort4 u1 = *(const ushort4*)(ybuf + r1 + d);
  ushort4 u2 = *(const ushort4*)(ybuf + r2 + d);
  f32x4 o;
  o[0] = g1 * bf2f(u1.x) + g2 * bf2f(u2.x);
  o[1] = g1 * bf2f(u1.y) + g2 * bf2f(u2.y);
  o[2] = g1 * bf2f(u1.z) + g2 * bf2f(u2.z);
  o[3] = g1 * bf2f(u1.w) + g2 * bf2f(u2.w);
  *(f32x4*)(out + (size_t)t * DIM + d) = o;
}

extern "C" void kernel_launch(void* const* d_in, const int* in_sizes, int n_in,
                              void* d_out, int out_size, void* d_ws, size_t ws_size,
                              hipStream_t stream) {
  const float* x     = (const float*)d_in[0];
  const float* noise = (const float*)d_in[1];
  const float* Wg    = (const float*)d_in[2];
  const float* bg    = (const float*)d_in[3];
  const float* Wn    = (const float*)d_in[4];
  const float* bn    = (const float*)d_in[5];
  const float* W1    = (const float*)d_in[6];
  const float* b1    = (const float*)d_in[7];
  const float* W2    = (const float*)d_in[8];
  const float* b2    = (const float*)d_in[9];
  float* out = (float*)d_out;

  char* ws = (char*)d_ws;
  int*            cnt    = (int*)(ws + 0);
  int*            hoff   = (int*)(ws + 32);
  int*            meta   = (int*)(ws + 64);    // rboff[0..8] + nrb_tot
  int*            tokL   = (int*)(ws + 256);
  float*          gateL  = (float*)(ws + 266496);
  unsigned short* xb     = (unsigned short*)(ws + 532736);     // ends 17,309,952
  unsigned short* ybuf   = (unsigned short*)(ws + 17309952);   // 35.7 MB (fits old w1t slot)
  unsigned short* hbuf   = (unsigned short*)(ws + 151527680);
  int*            tokmap = (int*)(ws + 294134016);
  // layout stays within the previously-working 294,199,552 bytes

  hipMemsetAsync(cnt, 0, 64, stream);

  router_kernel<<<TOK / 4, 256, 0, stream>>>(x, noise, Wg, bg, Wn, bn, cnt, tokL, gateL, tokmap, xb);
  pad_kernel<<<1, 256, 0, stream>>>(cnt, hoff, tokL, gateL, meta);
  // gemm1: h = relu(gather(xb) @ W1 + b1), W1 fp32 [E][1024][4096] consumed directly
  gemm_fused_kernel<DIM, HID, 32, true, true>
      <<<MAXRB * 32, 256, 0, stream>>>(xb, W1, b1, tokL, meta, hoff, hbuf);
  // gemm2: ybuf = hbuf @ W2 + b2, W2 fp32 [E][4096][1024] consumed directly
  gemm_fused_kernel<HID, DIM, 8, false, false>
      <<<MAXRB * 8, 256, 0, stream>>>(hbuf, W2, b2, tokL, meta, hoff, ybuf);
  combine_kernel<<<TOK, 256, 0, stream>>>(ybuf, tokmap, gateL, hoff, out);
}